// Round 6
// baseline (27927.048 us; speedup 1.0000x reference)
//
#include <hip/hip_runtime.h>
#include <stdint.h>

typedef unsigned int uint_t;

#define S_SEG 8192
#define CIN 128
#define COUT 256
#define LN_EPS 1e-5f

// order-preserving f32 <-> u32 keys for atomicMax-based float max
__device__ __forceinline__ uint_t fkey(float f) {
  uint_t b = __float_as_uint(f);
  return (b & 0x80000000u) ? ~b : (b | 0x80000000u);
}
__device__ __forceinline__ float funkey(uint_t k) {
  uint_t b = (k & 0x80000000u) ? (k ^ 0x80000000u) : ~k;
  return __uint_as_float(b);
}

// K0: init encoded-max buffer to key(-inf) = 0x007FFFFF
__global__ void k_xm_init(uint_t* __restrict__ enc) {
  enc[blockIdx.x * blockDim.x + threadIdx.x] = 0x007FFFFFu;
}

// K1: segment max via atomicMax on encoded floats (order-independent, exact).
__global__ void k_xm_scatter(const float* __restrict__ x, const int* __restrict__ batch,
                             uint_t* __restrict__ enc, int N) {
  int r0 = blockIdx.x * 32;
  int c = threadIdx.x;  // 128 threads = channels
  int rend = r0 + 32; if (rend > N) rend = N;
  int cur = batch[r0];
  float m = -INFINITY;
  for (int r = r0; r < rend; ++r) {
    int b = batch[r];
    if (b != cur) {
      atomicMax(&enc[(size_t)cur * CIN + c], fkey(m));
      cur = b;
      m = -INFINITY;
    }
    m = fmaxf(m, x[(size_t)r * CIN + c]);
  }
  atomicMax(&enc[(size_t)cur * CIN + c], fkey(m));
}

// K2: decode in place; -inf (empty segment) -> 0 per reference
__global__ void k_xm_decode(uint_t* __restrict__ enc, float* __restrict__ xm) {
  int i = blockIdx.x * blockDim.x + threadIdx.x;
  float f = funkey(enc[i]);
  xm[i] = (f >= -3.0e38f && f <= 3.0e38f) ? f : 0.0f;
}

// K3: xml[s][o] = gamma_b[o] - dot(xm[s,:], lambda_w[o,:])
// Dumbest possible form: one thread per (s,o), scalar f32 loop.
__global__ void k_lambda_f32(const float* __restrict__ xm, const float* __restrict__ lw,
                             const float* __restrict__ gb, float* __restrict__ xml) {
  int s = blockIdx.x;   // 0..8191
  int o = threadIdx.x;  // 0..255
  const float* xr = xm + (size_t)s * CIN;
  const float* wr = lw + (size_t)o * CIN;
  float acc = 0.f;
  for (int c = 0; c < CIN; ++c) acc += xr[c] * wr[c];
  xml[(size_t)s * COUT + o] = gb[o] - acc;
}

// K4: fused  out = PReLU(LN(x@gamma_w^T + xml[batch]))
// ALL-F32 VALU version: no MFMA, no bf16, no LDS tiles. 16 rows per block.
// Thread t: local row r=t>>4, cols c0=(t&15)+16j. LN reduced across the
// 16-lane group that owns one row (lanes r*16..r*16+15 of one wave).
__global__ __launch_bounds__(256) void k_main_f32(
    const float* __restrict__ x, const int* __restrict__ batch,
    const float* __restrict__ gw, const float* __restrict__ xml,
    const float* __restrict__ lnw, const float* __restrict__ lnb,
    const float* __restrict__ prelu, float* __restrict__ out, int N) {
  const int t = threadIdx.x;
  const int r = t >> 4;
  const int c0 = t & 15;
  const size_t row = (size_t)blockIdx.x * 16 + r;
  if (row >= (size_t)N) return;  // grid is exact for N=1e6 anyway

  float acc[16];
#pragma unroll
  for (int j = 0; j < 16; ++j) acc[j] = 0.f;

  const float* xr = x + row * CIN;
  for (int k = 0; k < CIN; ++k) {
    float xv = xr[k];
#pragma unroll
    for (int j = 0; j < 16; ++j)
      acc[j] += xv * gw[(size_t)(c0 + j * 16) * CIN + k];
  }

  const float* xmlr = xml + (size_t)batch[row] * COUT;
  float sum = 0.f, ssq = 0.f;
#pragma unroll
  for (int j = 0; j < 16; ++j) {
    float v = acc[j] + xmlr[c0 + j * 16];
    acc[j] = v;
    sum += v;
    ssq += v * v;
  }
#pragma unroll
  for (int m = 1; m < 16; m <<= 1) {  // reduce across the row's 16 lanes
    sum += __shfl_xor(sum, m);
    ssq += __shfl_xor(ssq, m);
  }
  float mu = sum * (1.f / 256.f);
  float var = ssq * (1.f / 256.f) - mu * mu;
  float rs = rsqrtf(var + LN_EPS);
  float a = prelu[0];

  float* orow = out + row * COUT;
#pragma unroll
  for (int j = 0; j < 16; ++j) {
    int c = c0 + j * 16;
    float v = (acc[j] - mu) * rs * lnw[c] + lnb[c];
    orow[c] = (v >= 0.f) ? v : a * v;
  }
}

extern "C" void kernel_launch(void* const* d_in, const int* in_sizes, int n_in,
                              void* d_out, int out_size, void* d_ws, size_t ws_size,
                              hipStream_t stream) {
  const float* x     = (const float*)d_in[0];
  const int*   batch = (const int*)d_in[1];
  const float* gw    = (const float*)d_in[2];
  const float* gb    = (const float*)d_in[3];
  const float* lw    = (const float*)d_in[4];
  const float* lnw   = (const float*)d_in[5];
  const float* lnb   = (const float*)d_in[6];
  const float* pa    = (const float*)d_in[7];
  float* out = (float*)d_out;
  const int N = in_sizes[0] / CIN;

  // ws layout: enc/xm (aliased, 4MB) | xml (8MB)
  char* w8 = (char*)d_ws;
  uint_t* enc = (uint_t*)w8;
  float* xm   = (float*)w8;                  // alias of enc after in-place decode
  float* xml  = (float*)(w8 + 4194304);

  k_xm_init<<<(S_SEG * CIN) / 256, 256, 0, stream>>>(enc);
  k_xm_scatter<<<(N + 31) / 32, CIN, 0, stream>>>(x, batch, enc, N);
  k_xm_decode<<<(S_SEG * CIN) / 256, 256, 0, stream>>>(enc, xm);
  k_lambda_f32<<<S_SEG, COUT, 0, stream>>>(xm, lw, gb, xml);
  k_main_f32<<<(N + 15) / 16, 256, 0, stream>>>(x, batch, gw, xml, lnw, lnb, pa, out, N);
}

// Round 9
// 9011.639 us; speedup vs baseline: 3.0990x; 3.0990x over previous
//
#include <hip/hip_runtime.h>
#include <stdint.h>

typedef unsigned int uint_t;

#define S_SEG 8192
#define CIN 128
#define COUT 256
#define LN_EPS 1e-5f
#define XLD 36   // padded LDS leading dim (floats): 144B, 16B-aligned, bank-staggered

// order-preserving f32 <-> u32 keys for atomicMax-based float max
__device__ __forceinline__ uint_t fkey(float f) {
  uint_t b = __float_as_uint(f);
  return (b & 0x80000000u) ? ~b : (b | 0x80000000u);
}
__device__ __forceinline__ float funkey(uint_t k) {
  uint_t b = (k & 0x80000000u) ? (k ^ 0x80000000u) : ~k;
  return __uint_as_float(b);
}

// K0: init encoded-max buffer to key(-inf)   [R6-verbatim, passing]
__global__ void k_xm_init(uint_t* __restrict__ enc) {
  enc[blockIdx.x * blockDim.x + threadIdx.x] = 0x007FFFFFu;
}

// K1: segment max via atomicMax on encoded floats   [R6-verbatim, passing]
__global__ void k_xm_scatter(const float* __restrict__ x, const int* __restrict__ batch,
                             uint_t* __restrict__ enc, int N) {
  int r0 = blockIdx.x * 32;
  int c = threadIdx.x;  // 128 threads = channels
  int rend = r0 + 32; if (rend > N) rend = N;
  int cur = batch[r0];
  float m = -INFINITY;
  for (int r = r0; r < rend; ++r) {
    int b = batch[r];
    if (b != cur) {
      atomicMax(&enc[(size_t)cur * CIN + c], fkey(m));
      cur = b;
      m = -INFINITY;
    }
    m = fmaxf(m, x[(size_t)r * CIN + c]);
  }
  atomicMax(&enc[(size_t)cur * CIN + c], fkey(m));
}

// K2: decode in place; -inf (empty segment) -> 0   [R6-verbatim, passing]
__global__ void k_xm_decode(uint_t* __restrict__ enc, float* __restrict__ xm) {
  int i = blockIdx.x * blockDim.x + threadIdx.x;
  float f = funkey(enc[i]);
  xm[i] = (f >= -3.0e38f && f <= 3.0e38f) ? f : 0.0f;
}

// K3: xml[s][o] = gamma_b[o] - dot(xm[s,:], lambda_w[o,:])   [R6-verbatim, passing]
__global__ void k_lambda_f32(const float* __restrict__ xm, const float* __restrict__ lw,
                             const float* __restrict__ gb, float* __restrict__ xml) {
  int s = blockIdx.x;   // 0..8191
  int o = threadIdx.x;  // 0..255
  const float* xr = xm + (size_t)s * CIN;
  const float* wr = lw + (size_t)o * CIN;
  float acc = 0.f;
  for (int c = 0; c < CIN; ++c) acc += xr[c] * wr[c];
  xml[(size_t)s * COUT + o] = gb[o] - acc;
}

// K4: fused  out = PReLU(LN(x@gamma_w^T + xml[batch]))
// PURE F32 VALU (R6 math), LDS-tiled for speed. 64 rows/block, 256 threads.
// Thread (ty=t>>4, tx=t&15): rows ty*4+ri (ri=0..3), cols tx+16j (j=0..15)
// -- the exact R6 column partition, so the LN/epilogue is R6-verbatim.
__global__ __launch_bounds__(256, 2) void k_main_f32t(
    const float* __restrict__ x, const int* __restrict__ batch,
    const float* __restrict__ gw, const float* __restrict__ xml,
    const float* __restrict__ lnw, const float* __restrict__ lnb,
    const float* __restrict__ prelu, float* __restrict__ out, int N) {
  __shared__ float xs[64 * XLD];    //  9216 B  x-tile  [64 rows][32 k]
  __shared__ float ws[256 * XLD];   // 36864 B  gw-tile [256 cols][32 k]

  const int tid = threadIdx.x;
  const int ty = tid >> 4;
  const int tx = tid & 15;
  const size_t row0 = (size_t)blockIdx.x * 64;
  const float aslope = prelu[0];

  float acc[4][16];
#pragma unroll
  for (int ri = 0; ri < 4; ++ri)
#pragma unroll
    for (int j = 0; j < 16; ++j) acc[ri][j] = 0.f;

  for (int kt = 0; kt < 4; ++kt) {   // K tiled by 32
    if (kt) __syncthreads();
    // stage x-tile: 64 rows x 8 float4-chunks = 512, 2 per thread
#pragma unroll
    for (int cc = 0; cc < 2; ++cc) {
      int c = tid + cc * 256;
      int r = c >> 3, ch = c & 7;
      size_t gr = row0 + r;
      if (gr >= (size_t)N) gr = (size_t)N - 1;  // never fires for N%64==0
      float4 v = *(const float4*)(x + gr * CIN + kt * 32 + ch * 4);
      *(float4*)&xs[r * XLD + ch * 4] = v;
    }
    // stage gw-tile: 256 rows x 8 chunks = 2048, 8 per thread
#pragma unroll
    for (int cc = 0; cc < 8; ++cc) {
      int c = tid + cc * 256;
      int r = c >> 3, ch = c & 7;
      float4 v = *(const float4*)(gw + (size_t)r * CIN + kt * 32 + ch * 4);
      *(float4*)&ws[r * XLD + ch * 4] = v;
    }
    __syncthreads();
    // compute: 8 k-chunks of 4
#pragma unroll
    for (int kc = 0; kc < 8; ++kc) {
      float4 xv0 = *(const float4*)&xs[(ty * 4 + 0) * XLD + kc * 4];
      float4 xv1 = *(const float4*)&xs[(ty * 4 + 1) * XLD + kc * 4];
      float4 xv2 = *(const float4*)&xs[(ty * 4 + 2) * XLD + kc * 4];
      float4 xv3 = *(const float4*)&xs[(ty * 4 + 3) * XLD + kc * 4];
#pragma unroll
      for (int j = 0; j < 16; ++j) {
        float4 wv = *(const float4*)&ws[(tx + 16 * j) * XLD + kc * 4];
        acc[0][j] += xv0.x * wv.x + xv0.y * wv.y + xv0.z * wv.z + xv0.w * wv.w;
        acc[1][j] += xv1.x * wv.x + xv1.y * wv.y + xv1.z * wv.z + xv1.w * wv.w;
        acc[2][j] += xv2.x * wv.x + xv2.y * wv.y + xv2.z * wv.z + xv2.w * wv.w;
        acc[3][j] += xv3.x * wv.x + xv3.y * wv.y + xv3.z * wv.z + xv3.w * wv.w;
      }
    }
  }

  // epilogue: R6-verbatim pattern per row (direct batch[], scalar xml/lnw/out)
#pragma unroll
  for (int ri = 0; ri < 4; ++ri) {
    size_t row = row0 + (size_t)(ty * 4 + ri);
    if (row >= (size_t)N) continue;
    const float* xmlr = xml + (size_t)batch[row] * COUT;
    float sum = 0.f, ssq = 0.f;
#pragma unroll
    for (int j = 0; j < 16; ++j) {
      float v = acc[ri][j] + xmlr[tx + 16 * j];
      acc[ri][j] = v;
      sum += v;
      ssq += v * v;
    }
#pragma unroll
    for (int m = 1; m < 16; m <<= 1) {  // reduce across the row's 16 lanes
      sum += __shfl_xor(sum, m);
      ssq += __shfl_xor(ssq, m);
    }
    float mu = sum * (1.f / 256.f);
    float var = ssq * (1.f / 256.f) - mu * mu;
    float rs = rsqrtf(var + LN_EPS);
    float* orow = out + row * COUT;
#pragma unroll
    for (int j = 0; j < 16; ++j) {
      int c = tx + 16 * j;
      float v = (acc[ri][j] - mu) * rs * lnw[c] + lnb[c];
      orow[c] = (v >= 0.f) ? v : aslope * v;
    }
  }
}

extern "C" void kernel_launch(void* const* d_in, const int* in_sizes, int n_in,
                              void* d_out, int out_size, void* d_ws, size_t ws_size,
                              hipStream_t stream) {
  const float* x     = (const float*)d_in[0];
  const int*   batch = (const int*)d_in[1];
  const float* gw    = (const float*)d_in[2];
  const float* gb    = (const float*)d_in[3];
  const float* lw    = (const float*)d_in[4];
  const float* lnw   = (const float*)d_in[5];
  const float* lnb   = (const float*)d_in[6];
  const float* pa    = (const float*)d_in[7];
  float* out = (float*)d_out;
  const int N = in_sizes[0] / CIN;

  // ws, TOTAL 12 MB (R6-verified): enc/xm (aliased, 4MB) | xml (8MB)
  char* w8 = (char*)d_ws;
  uint_t* enc = (uint_t*)w8;
  float* xm   = (float*)w8;                  // alias of enc (in-place decode)
  float* xml  = (float*)(w8 + 4194304);

  k_xm_init<<<(S_SEG * CIN) / 256, 256, 0, stream>>>(enc);
  k_xm_scatter<<<(N + 31) / 32, CIN, 0, stream>>>(x, batch, enc, N);
  k_xm_decode<<<(S_SEG * CIN) / 256, 256, 0, stream>>>(enc, xm);
  k_lambda_f32<<<S_SEG, COUT, 0, stream>>>(xm, lw, gb, xml);
  k_main_f32t<<<(N + 63) / 64, 256, 0, stream>>>(x, batch, gw, xml, lnw, lnb, pa, out, N);
}

// Round 10
// 2627.558 us; speedup vs baseline: 10.6285x; 3.4297x over previous
//
#include <hip/hip_runtime.h>
#include <stdint.h>

typedef unsigned int uint_t;

#define S_SEG 8192
#define CIN 128
#define COUT 256
#define LN_EPS 1e-5f
#define BM 32    // rows per block in k_main_v3
#define XLD 132  // padded LDS leading dim (floats)

// order-preserving f32 <-> u32 keys for atomicMax-based float max
__device__ __forceinline__ uint_t fkey(float f) {
  uint_t b = __float_as_uint(f);
  return (b & 0x80000000u) ? ~b : (b | 0x80000000u);
}
__device__ __forceinline__ float funkey(uint_t k) {
  uint_t b = (k & 0x80000000u) ? (k ^ 0x80000000u) : ~k;
  return __uint_as_float(b);
}

// K0: init encoded-max buffer to key(-inf)   [R6-verbatim, passing]
__global__ void k_xm_init(uint_t* __restrict__ enc) {
  enc[blockIdx.x * blockDim.x + threadIdx.x] = 0x007FFFFFu;
}

// K1: segment max via atomicMax on encoded floats   [R6-verbatim, passing]
__global__ void k_xm_scatter(const float* __restrict__ x, const int* __restrict__ batch,
                             uint_t* __restrict__ enc, int N) {
  int r0 = blockIdx.x * 32;
  int c = threadIdx.x;  // 128 threads = channels
  int rend = r0 + 32; if (rend > N) rend = N;
  int cur = batch[r0];
  float m = -INFINITY;
  for (int r = r0; r < rend; ++r) {
    int b = batch[r];
    if (b != cur) {
      atomicMax(&enc[(size_t)cur * CIN + c], fkey(m));
      cur = b;
      m = -INFINITY;
    }
    m = fmaxf(m, x[(size_t)r * CIN + c]);
  }
  atomicMax(&enc[(size_t)cur * CIN + c], fkey(m));
}

// K2: decode in place; -inf (empty segment) -> 0   [R6-verbatim, passing]
__global__ void k_xm_decode(uint_t* __restrict__ enc, float* __restrict__ xm) {
  int i = blockIdx.x * blockDim.x + threadIdx.x;
  float f = funkey(enc[i]);
  xm[i] = (f >= -3.0e38f && f <= 3.0e38f) ? f : 0.0f;
}

// K3: xml[s][o] = gamma_b[o] - dot(xm[s,:], lambda_w[o,:])   [R6-verbatim, passing]
__global__ void k_lambda_f32(const float* __restrict__ xm, const float* __restrict__ lw,
                             const float* __restrict__ gb, float* __restrict__ xml) {
  int s = blockIdx.x;   // 0..8191
  int o = threadIdx.x;  // 0..255
  const float* xr = xm + (size_t)s * CIN;
  const float* wr = lw + (size_t)o * CIN;
  float acc = 0.f;
  for (int c = 0; c < CIN; ++c) acc += xr[c] * wr[c];
  xml[(size_t)s * COUT + o] = gb[o] - acc;
}

// K3b: transpose gw -> gwT[k][cout] (128 KB). Runs AFTER k_lambda, overwrites
// the dead xm region; total ws stays at the verified 12 MB.
__global__ void k_gwT(const float* __restrict__ gw, float* __restrict__ gwT) {
  int i = blockIdx.x * blockDim.x + threadIdx.x;  // 32768
  int k = i >> 8, c = i & 255;
  gwT[(size_t)k * COUT + c] = gw[(size_t)c * CIN + k];
}

// K4 v3: out = PReLU(LN(x@gwT + xml[batch]))
// 256 threads, BM=32 rows. Wave ty (=tid>>6) owns rows ty*8..ty*8+7; thread
// owns 4 consecutive cols c0=(tid&63)*4. acc = 8 float4 = 32 VGPR -> no spill.
// One barrier per block; gwT loads 1KB-coalesced from L2; x via LDS broadcast.
__global__ __launch_bounds__(256, 4) void k_main_v3(
    const float* __restrict__ x, const int* __restrict__ batch,
    const float* __restrict__ gwT, const float* __restrict__ xml,
    const float* __restrict__ lnw, const float* __restrict__ lnb,
    const float* __restrict__ prelu, float* __restrict__ out, int N) {
  __shared__ float xs[BM * XLD];  // 16.9 KB

  const int tid = threadIdx.x;
  const int ty = tid >> 6;        // wave id = row group
  const int tx = tid & 63;
  const int c0 = tx * 4;
  const size_t row0 = (size_t)blockIdx.x * BM;

  // stage x rows [row0, row0+BM) x 128k  (1024 float4 chunks, 4 per thread)
#pragma unroll
  for (int cc = 0; cc < 4; ++cc) {
    int c = tid + cc * 256;
    int r = c >> 5, ch = c & 31;
    size_t gr = row0 + r;
    if (gr >= (size_t)N) gr = (size_t)N - 1;  // N%32==0: never fires
    *(float4*)&xs[r * XLD + ch * 4] = *(const float4*)(x + gr * CIN + ch * 4);
  }
  __syncthreads();

  float4 acc[8];
#pragma unroll
  for (int r = 0; r < 8; ++r) acc[r] = (float4){0.f, 0.f, 0.f, 0.f};

#pragma unroll 4
  for (int kc = 0; kc < 32; ++kc) {  // k in chunks of 4
    const float* gk = gwT + (size_t)(kc * 4) * COUT + c0;
    float4 w0 = *(const float4*)(gk);
    float4 w1 = *(const float4*)(gk + COUT);
    float4 w2 = *(const float4*)(gk + 2 * COUT);
    float4 w3 = *(const float4*)(gk + 3 * COUT);
#pragma unroll
    for (int r = 0; r < 8; ++r) {
      float4 xv = *(const float4*)&xs[(ty * 8 + r) * XLD + kc * 4];  // wave-broadcast
      acc[r].x += xv.x * w0.x + xv.y * w1.x + xv.z * w2.x + xv.w * w3.x;
      acc[r].y += xv.x * w0.y + xv.y * w1.y + xv.z * w2.y + xv.w * w3.y;
      acc[r].z += xv.x * w0.z + xv.y * w1.z + xv.z * w2.z + xv.w * w3.z;
      acc[r].w += xv.x * w0.w + xv.y * w1.w + xv.z * w2.w + xv.w * w3.w;
    }
  }

  // epilogue: whole wave handles one row at a time -> 64-lane LN reduce
  const float4 lw4 = *(const float4*)(lnw + c0);
  const float4 lb4 = *(const float4*)(lnb + c0);
  const float asl = prelu[0];
#pragma unroll
  for (int r = 0; r < 8; ++r) {
    size_t row = row0 + (size_t)(ty * 8 + r);
    if (row >= (size_t)N) continue;         // wave-uniform
    const float* xmlr = xml + (size_t)batch[row] * COUT;
    float4 m4 = *(const float4*)(xmlr + c0);
    float4 v;
    v.x = acc[r].x + m4.x; v.y = acc[r].y + m4.y;
    v.z = acc[r].z + m4.z; v.w = acc[r].w + m4.w;
    float sum = v.x + v.y + v.z + v.w;
    float ssq = v.x * v.x + v.y * v.y + v.z * v.z + v.w * v.w;
#pragma unroll
    for (int m = 1; m < 64; m <<= 1) {      // full-wave reduce over 256 cols
      sum += __shfl_xor(sum, m);
      ssq += __shfl_xor(ssq, m);
    }
    float mu = sum * (1.f / 256.f);
    float var = ssq * (1.f / 256.f) - mu * mu;
    float rs = rsqrtf(var + LN_EPS);
    float4 o; float t;
    t = (v.x - mu) * rs * lw4.x + lb4.x; o.x = (t >= 0.f) ? t : asl * t;
    t = (v.y - mu) * rs * lw4.y + lb4.y; o.y = (t >= 0.f) ? t : asl * t;
    t = (v.z - mu) * rs * lw4.z + lb4.z; o.z = (t >= 0.f) ? t : asl * t;
    t = (v.w - mu) * rs * lw4.w + lb4.w; o.w = (t >= 0.f) ? t : asl * t;
    *(float4*)(out + row * COUT + c0) = o;
  }
}

extern "C" void kernel_launch(void* const* d_in, const int* in_sizes, int n_in,
                              void* d_out, int out_size, void* d_ws, size_t ws_size,
                              hipStream_t stream) {
  const float* x     = (const float*)d_in[0];
  const int*   batch = (const int*)d_in[1];
  const float* gw    = (const float*)d_in[2];
  const float* gb    = (const float*)d_in[3];
  const float* lw    = (const float*)d_in[4];
  const float* lnw   = (const float*)d_in[5];
  const float* lnb   = (const float*)d_in[6];
  const float* pa    = (const float*)d_in[7];
  float* out = (float*)d_out;
  const int N = in_sizes[0] / CIN;

  // ws, TOTAL 12 MB (verified): [0,4MB) enc/xm, gwT reuses it after k_lambda;
  // [4MB,12MB) xml.
  char* w8 = (char*)d_ws;
  uint_t* enc = (uint_t*)w8;
  float* xm   = (float*)w8;                  // alias of enc (in-place decode)
  float* gwT  = (float*)w8;                  // alias of xm, valid AFTER k_lambda
  float* xml  = (float*)(w8 + 4194304);

  k_xm_init<<<(S_SEG * CIN) / 256, 256, 0, stream>>>(enc);
  k_xm_scatter<<<(N + 31) / 32, CIN, 0, stream>>>(x, batch, enc, N);
  k_xm_decode<<<(S_SEG * CIN) / 256, 256, 0, stream>>>(enc, xm);
  k_lambda_f32<<<S_SEG, COUT, 0, stream>>>(xm, lw, gb, xml);
  k_gwT<<<(COUT * CIN) / 256, 256, 0, stream>>>(gw, gwT);  // xm dead now
  k_main_v3<<<(N + BM - 1) / BM, 256, 0, stream>>>(x, batch, gwT, xml, lnw, lnb, pa, out, N);
}